// Round 1
// baseline (9267.101 us; speedup 1.0000x reference)
//
#include <hip/hip_runtime.h>

typedef unsigned short u16;
typedef __bf16 bf16x8 __attribute__((ext_vector_type(8)));
typedef float f32x4 __attribute__((ext_vector_type(4)));

#define AS1 __attribute__((address_space(1)))
#define AS3 __attribute__((address_space(3)))

// Constants for this problem
// B=256, A=5, T=64, NIN=4, NHID=256, L=2, H=1280, 4H=5120, steps=63

__device__ __forceinline__ u16 f2bf(float f) {
    union { float f; unsigned int u; } v; v.f = f;
    unsigned int r = v.u + 0x7fffu + ((v.u >> 16) & 1u);
    return (u16)(r >> 16);
}

__device__ __forceinline__ void ld_lds16(const u16* g, u16* l) {
    __builtin_amdgcn_global_load_lds((AS1 unsigned int*)(unsigned long long)(const void*)g,
                                     (AS3 unsigned int*)l, 16, 0, 0);
}

__device__ __forceinline__ float sigm(float x) { return 1.f / (1.f + __expf(-x)); }
__device__ __forceinline__ float tanh_f(float x) { return 1.f - 2.f / (__expf(2.f * x) + 1.f); }

// ---------------------------------------------------------------------------
// fp32 -> bf16 conversion (grid-stride, float4)
// ---------------------------------------------------------------------------
__global__ __launch_bounds__(256) void cvt_kernel(const float* __restrict__ src,
                                                  u16* __restrict__ dst, int n) {
    int i = (blockIdx.x * 256 + threadIdx.x) * 4;
    int stride = gridDim.x * 256 * 4;
    for (; i < n; i += stride) {
        float4 v = *(const float4*)(src + i);
        ushort4 o;
        o.x = f2bf(v.x); o.y = f2bf(v.y); o.z = f2bf(v.z); o.w = f2bf(v.w);
        *(ushort4*)(dst + i) = o;
    }
}

// ---------------------------------------------------------------------------
// GEMM: C[M x N] = A[M x K](bf16) @ Bm[N x K](bf16)^T  (+Cadd) (+bias) (relu)
// BM=64, BN=128, BK=32. Block 256 threads = 4 waves in 2x2 wave grid, each
// wave computes 32x64 via 2x4 MFMA 16x16x32 fragments. global_load_lds
// staging (wave-uniform LDS base + lane*16B). Exact tiling: M%64==0,
// N%128==0, K%32==0 guaranteed by caller.
// A-select: A += (n0 / n_sel) * a_sel  (used for the 2-layer w_hh GEMM).
// ---------------------------------------------------------------------------
template <int ADDC, int BIAS, int RELU>
__global__ __launch_bounds__(256) void gemm_bt(
    const u16* A, int lda,
    const u16* __restrict__ Bm, int ldb,
    const float* __restrict__ Cadd, int ldcadd,
    const float* __restrict__ bias,
    float* __restrict__ C, int ldc,
    int K, int n_sel, long long a_sel) {
    __shared__ __align__(16) u16 As[64 * 32];
    __shared__ __align__(16) u16 Bs[128 * 32];

    int tid = threadIdx.x;
    int wid = tid >> 6, lane = tid & 63;
    int wm = wid >> 1, wn = wid & 1;
    int q = lane >> 4, m16 = lane & 15;
    int n0 = blockIdx.x * 128, m0 = blockIdx.y * 64;
    A += (long long)(n0 / n_sel) * a_sel;

    f32x4 acc[2][4];
#pragma unroll
    for (int i = 0; i < 2; i++)
#pragma unroll
        for (int j = 0; j < 4; j++) acc[i][j] = (f32x4){0.f, 0.f, 0.f, 0.f};

    const int ak = (tid & 3) * 8;
    const u16* aptr = A + (size_t)(m0 + (tid >> 2)) * lda + ak;
    const u16* bptr0 = Bm + (size_t)(n0 + (tid >> 2)) * ldb + ak;
    const u16* bptr1 = Bm + (size_t)(n0 + 64 + (tid >> 2)) * ldb + ak;
    u16* aDst = As + wid * 512;        // 1KB per wave
    u16* bDst0 = Bs + wid * 512;
    u16* bDst1 = Bs + 2048 + wid * 512;

    for (int kt = 0; kt < K; kt += 32) {
        ld_lds16(aptr, aDst);
        ld_lds16(bptr0, bDst0);
        ld_lds16(bptr1, bDst1);
        aptr += 32; bptr0 += 32; bptr1 += 32;
        __syncthreads();

        bf16x8 af[2], bfr[4];
#pragma unroll
        for (int i = 0; i < 2; i++)
            af[i] = *(const bf16x8*)&As[(wm * 32 + i * 16 + m16) * 32 + q * 8];
#pragma unroll
        for (int j = 0; j < 4; j++)
            bfr[j] = *(const bf16x8*)&Bs[(wn * 64 + j * 16 + m16) * 32 + q * 8];
#pragma unroll
        for (int i = 0; i < 2; i++)
#pragma unroll
            for (int j = 0; j < 4; j++)
                acc[i][j] = __builtin_amdgcn_mfma_f32_16x16x32_bf16(af[i], bfr[j], acc[i][j], 0, 0, 0);
        __syncthreads();
    }

#pragma unroll
    for (int i = 0; i < 2; i++) {
        int row = m0 + wm * 32 + i * 16 + q * 4;
#pragma unroll
        for (int j = 0; j < 4; j++) {
            int col = n0 + wn * 64 + j * 16 + m16;
#pragma unroll
            for (int r = 0; r < 4; r++) {
                float v = acc[i][j][r];
                if (ADDC) v += Cadd[(size_t)(row + r) * ldcadd + col];
                if (BIAS) v += bias[col];
                if (RELU) v = fmaxf(v, 0.f);
                C[(size_t)(row + r) * ldc + col] = v;
            }
        }
    }
}

// ---------------------------------------------------------------------------
// MLP: ins select (teacher forcing) + layer1 (4->256) + layer2 (256->256)
// One block = 8 samples (s = b*5+a). 160 blocks x 256 threads.
// Writes ins_buf [256][20] and x_bf [256][1280] (== [1280 samples][256]) bf16.
// ---------------------------------------------------------------------------
__global__ __launch_bounds__(256) void mlp_kernel(
    const float* __restrict__ inputs, const float* __restrict__ prev,
    const float* __restrict__ w11, const float* __restrict__ b11,
    const float* __restrict__ w12, const float* __restrict__ b12,
    const int* __restrict__ ps, int t,
    float* __restrict__ ins_buf, u16* __restrict__ x_bf) {
    __shared__ float ins_s[8][4];
    __shared__ float act1[8][256];
    int tid = threadIdx.x;
    int s0 = blockIdx.x * 8;
    bool teacher = (t % ps[0]) == 0;
    if (tid < 32) {
        int sl = tid >> 2, k = tid & 3;
        int s = s0 + sl;
        float v = teacher ? inputs[((size_t)s * 64 + t) * 4 + k] : prev[s * 4 + k];
        ins_s[sl][k] = v;
        ins_buf[s * 4 + k] = v;
    }
    __syncthreads();
    int j = tid;
    float4 w = *(const float4*)(w11 + j * 4);
    float bb1 = b11[j];
#pragma unroll
    for (int g = 0; g < 8; g++) {
        float v = fmaf(w.x, ins_s[g][0],
                  fmaf(w.y, ins_s[g][1],
                  fmaf(w.z, ins_s[g][2],
                  fmaf(w.w, ins_s[g][3], bb1))));
        act1[g][j] = fmaxf(v, 0.f);
    }
    __syncthreads();
    float acc[8];
    float bb2 = b12[j];
#pragma unroll
    for (int g = 0; g < 8; g++) acc[g] = bb2;
#pragma unroll 4
    for (int k = 0; k < 256; k++) {
        float wv = w12[j * 256 + k];
#pragma unroll
        for (int g = 0; g < 8; g++) acc[g] = fmaf(wv, act1[g][k], acc[g]);
    }
#pragma unroll
    for (int g = 0; g < 8; g++)
        x_bf[(size_t)(s0 + g) * 256 + j] = f2bf(fmaxf(acc[g], 0.f));
}

// ---------------------------------------------------------------------------
// LSTM pointwise cell for one layer.
// gates [256][5120] = x@w_ih^T + h@w_hh^T (biases added here).
// Updates c (fp32) and writes h as bf16. 320 blocks x 256 thr x 4 elems.
// ---------------------------------------------------------------------------
__global__ __launch_bounds__(256) void cell_kernel(
    const float* __restrict__ gates, const float* __restrict__ bih,
    const float* __restrict__ bhh, float* __restrict__ c,
    u16* __restrict__ h_bf) {
    int e = (blockIdx.x * 256 + threadIdx.x) * 4;  // over 256*1280
    int b = e / 1280, j = e % 1280;
    const float* gr = gates + (size_t)b * 5120 + j;
    float cv[4];
    *(float4*)cv = *(const float4*)(c + e);
    u16 hb[4];
#pragma unroll
    for (int r = 0; r < 4; r++) {
        int jj = j + r;
        float i_ = gr[r]        + bih[jj]        + bhh[jj];
        float f_ = gr[1280 + r] + bih[1280 + jj] + bhh[1280 + jj];
        float g_ = gr[2560 + r] + bih[2560 + jj] + bhh[2560 + jj];
        float o_ = gr[3840 + r] + bih[3840 + jj] + bhh[3840 + jj];
        float cn = sigm(f_) * cv[r] + sigm(i_) * tanh_f(g_);
        cv[r] = cn;
        hb[r] = f2bf(sigm(o_) * tanh_f(cn));
    }
    *(float4*)(c + e) = *(float4*)cv;
    ushort4 h4; h4.x = hb[0]; h4.y = hb[1]; h4.z = hb[2]; h4.w = hb[3];
    *(ushort4*)(h_bf + e) = h4;
}

// ---------------------------------------------------------------------------
// Output head: out = y @ w2_2^T + b2_2 + ins. One wave per sample b.
// 64 blocks x 256 threads (4 waves). Writes d_out[b][a][t][n] and prev_out.
// ---------------------------------------------------------------------------
__global__ __launch_bounds__(256) void out_kernel(
    const float* __restrict__ y, const float* __restrict__ w22,
    const float* __restrict__ b22, const float* __restrict__ ins_buf,
    float* __restrict__ out, float* __restrict__ prev, int t) {
    int wid = threadIdx.x >> 6, lane = threadIdx.x & 63;
    int b = blockIdx.x * 4 + wid;
    const float* yb = y + (size_t)b * 1280;
    float acc[20];
#pragma unroll
    for (int j = 0; j < 20; j++) acc[j] = 0.f;
    for (int kk = 0; kk < 20; kk++) {
        int k = kk * 64 + lane;
        float yv = yb[k];
#pragma unroll
        for (int j = 0; j < 20; j++) acc[j] = fmaf(yv, w22[j * 1280 + k], acc[j]);
    }
#pragma unroll
    for (int j = 0; j < 20; j++) {
        float v = acc[j];
#pragma unroll
        for (int off = 32; off; off >>= 1) v += __shfl_xor(v, off);
        if (lane == j) {
            int a = j >> 2, n = j & 3;
            float r = v + b22[j] + ins_buf[b * 20 + j];
            out[(((size_t)b * 5 + a) * 63 + t) * 4 + n] = r;
            prev[b * 20 + j] = r;
        }
    }
}

// ---------------------------------------------------------------------------
extern "C" void kernel_launch(void* const* d_in, const int* in_sizes, int n_in,
                              void* d_out, int out_size, void* d_ws, size_t ws_size,
                              hipStream_t stream) {
    const float* inputs = (const float*)d_in[0];
    const float* w1_1 = (const float*)d_in[1];
    const float* b1_1 = (const float*)d_in[2];
    const float* w1_2 = (const float*)d_in[3];
    const float* b1_2 = (const float*)d_in[4];
    const float* w_ih = (const float*)d_in[5];
    const float* w_hh = (const float*)d_in[6];
    const float* b_ih = (const float*)d_in[7];
    const float* b_hh = (const float*)d_in[8];
    const float* w2_1 = (const float*)d_in[9];
    const float* b2_1 = (const float*)d_in[10];
    const float* w2_2 = (const float*)d_in[11];
    const float* b2_2 = (const float*)d_in[12];
    const int* ps = (const int*)d_in[13];
    float* out = (float*)d_out;

    char* ws = (char*)d_ws;
    size_t off = 0;
    auto alloc = [&](size_t bytes) -> void* {
        void* p = ws + off;
        off = (off + bytes + 255) & ~(size_t)255;
        return p;
    };
    u16* w_ih_bf = (u16*)alloc(13107200ull * 2);   // [2][5120][1280]
    u16* w_hh_bf = (u16*)alloc(13107200ull * 2);   // [2][5120][1280]
    u16* w21_bf  = (u16*)alloc(1638400ull * 2);    // [1280][1280]
    u16* h_bf    = (u16*)alloc(655360ull * 2);     // [2][256][1280]
    float* c_st  = (float*)alloc(655360ull * 4);   // [2][256][1280]
    u16* x_bf    = (u16*)alloc(327680ull * 2);     // [256][1280]
    float* ghh   = (float*)alloc(2621440ull * 4);  // [256][10240]
    float* gates = (float*)alloc(1310720ull * 4);  // [256][5120]
    float* yb    = (float*)alloc(327680ull * 4);   // [256][1280]
    float* ins_b = (float*)alloc(5120ull * 4);     // [256][20]
    float* prev  = (float*)alloc(5120ull * 4);     // [256][20]

    // one-time (per launch) weight conversion + state init
    cvt_kernel<<<2048, 256, 0, stream>>>(w_ih, w_ih_bf, 13107200);
    cvt_kernel<<<2048, 256, 0, stream>>>(w_hh, w_hh_bf, 13107200);
    cvt_kernel<<<512, 256, 0, stream>>>(w2_1, w21_bf, 1638400);
    hipMemsetAsync(h_bf, 0, 655360ull * 2, stream);
    hipMemsetAsync(c_st, 0, 655360ull * 4, stream);

    const int NSEL_OFF = 1 << 30;
    for (int t = 0; t < 63; t++) {
        // ins select + MLP -> x_bf
        mlp_kernel<<<160, 256, 0, stream>>>(inputs, prev, w1_1, b1_1, w1_2, b1_2,
                                            ps, t, ins_b, x_bf);
        // ghh = [h0;h1] @ [w_hh0;w_hh1]^T  (both layers, off critical path)
        gemm_bt<0, 0, 0><<<dim3(80, 4), 256, 0, stream>>>(
            h_bf, 1280, w_hh_bf, 1280, nullptr, 0, nullptr,
            ghh, 10240, 1280, 5120, 327680LL);
        // layer 0: gates = x @ w_ih0^T + ghh[:, :5120]
        gemm_bt<1, 0, 0><<<dim3(40, 4), 256, 0, stream>>>(
            x_bf, 1280, w_ih_bf, 1280, ghh, 10240, nullptr,
            gates, 5120, 1280, NSEL_OFF, 0LL);
        cell_kernel<<<320, 256, 0, stream>>>(gates, b_ih, b_hh, c_st, h_bf);
        // layer 1: gates = h0_new @ w_ih1^T + ghh[:, 5120:]
        gemm_bt<1, 0, 0><<<dim3(40, 4), 256, 0, stream>>>(
            h_bf, 1280, w_ih_bf + 6553600, 1280, ghh + 5120, 10240, nullptr,
            gates, 5120, 1280, NSEL_OFF, 0LL);
        cell_kernel<<<320, 256, 0, stream>>>(gates, b_ih + 5120, b_hh + 5120,
                                             c_st + 327680, h_bf + 327680);
        // y = relu(h1 @ w2_1^T + b2_1)
        gemm_bt<0, 1, 1><<<dim3(10, 4), 256, 0, stream>>>(
            h_bf + 327680, 1280, w21_bf, 1280, nullptr, 0, b2_1,
            yb, 1280, 1280, NSEL_OFF, 0LL);
        // out head + residual + write prev
        out_kernel<<<64, 256, 0, stream>>>(yb, w2_2, b2_2, ins_b, out, prev, t);
    }
}

// Round 2
// 6513.136 us; speedup vs baseline: 1.4228x; 1.4228x over previous
//
#include <hip/hip_runtime.h>

typedef unsigned short u16;
typedef __bf16 bf16x8 __attribute__((ext_vector_type(8)));
typedef float f32x4 __attribute__((ext_vector_type(4)));

#define AS1 __attribute__((address_space(1)))
#define AS3 __attribute__((address_space(3)))

// B=256, A=5, T=64, NIN=4, NHID=256, L=2, H=1280, 4H=5120, steps=63

__device__ __forceinline__ u16 f2bf(float f) {
    union { float f; unsigned int u; } v; v.f = f;
    unsigned int r = v.u + 0x7fffu + ((v.u >> 16) & 1u);
    return (u16)(r >> 16);
}

__device__ __forceinline__ void ld_lds16(const u16* g, u16* l) {
    __builtin_amdgcn_global_load_lds((AS1 unsigned int*)(unsigned long long)(const void*)g,
                                     (AS3 unsigned int*)l, 16, 0, 0);
}

__device__ __forceinline__ float sigm(float x) { return 1.f / (1.f + __expf(-x)); }
__device__ __forceinline__ float tanh_f(float x) { return 1.f - 2.f / (__expf(2.f * x) + 1.f); }

// ---------------------------------------------------------------------------
// fp32 -> bf16 (straight)
// ---------------------------------------------------------------------------
__global__ __launch_bounds__(256) void cvt_kernel(const float* __restrict__ src,
                                                  u16* __restrict__ dst, int n) {
    int i = (blockIdx.x * 256 + threadIdx.x) * 4;
    if (i >= n) return;
    float4 v = *(const float4*)(src + i);
    ushort4 o;
    o.x = f2bf(v.x); o.y = f2bf(v.y); o.z = f2bf(v.z); o.w = f2bf(v.w);
    *(ushort4*)(dst + i) = o;
}

// ---------------------------------------------------------------------------
// Build wcat[l][j*4+g][k] : k<1280 -> w_ih[l][g*1280+j][k], else w_hh[..][k-1280]
// Gate-interleaved rows + K-concat. Total 2*5120*2560 bf16.
// ---------------------------------------------------------------------------
__global__ __launch_bounds__(256) void cvt_wcat(const float* __restrict__ wih,
                                                const float* __restrict__ whh,
                                                u16* __restrict__ dst) {
    long long idx = ((long long)blockIdx.x * 256 + threadIdx.x) * 4;
    int k = (int)(idx % 2560);
    long long rr = idx / 2560;          // l*5120 + r'
    int l = (int)(rr / 5120), r = (int)(rr % 5120);
    int j = r >> 2, g = r & 3;
    long long srow = (long long)l * 5120 + g * 1280 + j;
    const float* s = (k < 1280) ? (wih + srow * 1280 + k) : (whh + srow * 1280 + (k - 1280));
    float4 v = *(const float4*)s;
    ushort4 o;
    o.x = f2bf(v.x); o.y = f2bf(v.y); o.z = f2bf(v.z); o.w = f2bf(v.w);
    *(ushort4*)(dst + idx) = o;
}

// ---------------------------------------------------------------------------
// Pipelined MFMA core: C_tile[64x128] += A[m0..][K] @ B[n0..][K]^T, BK=64,
// double-buffered global_load_lds with manual vmcnt + raw s_barrier.
// XOR-swizzled LDS: row-major [row][64] u16, granule g stored at g^(row&7).
// ---------------------------------------------------------------------------
__device__ __forceinline__ void gemm_core(
    const u16* A, int lda, const u16* Bw, int ldb, int K,
    int m0, int n0, u16* As, u16* Bs, f32x4 (&acc)[2][4]) {
    int tid = threadIdx.x;
    int w = tid >> 6, l = tid & 63;
    int wm = w >> 1, wn = w & 1;
    int q = l >> 4, m16 = l & 15;
    int r8 = l >> 3;
    int g8 = (l & 7) ^ r8;              // swizzled k-granule this lane loads

    const u16* aP = A + (size_t)(m0 + w * 8 + r8) * lda + g8 * 8;
    const u16* bP = Bw + (size_t)(n0 + w * 8 + r8) * ldb + g8 * 8;
    u16* aD = As + w * 512;
    u16* bD = Bs + w * 512;

    int nIter = K >> 6;
    // prologue: issue tile 0 into buf 0
    ld_lds16(aP, aD);
    ld_lds16(aP + (size_t)32 * lda, aD + 2048);
    ld_lds16(bP, bD);
    ld_lds16(bP + (size_t)32 * ldb, bD + 2048);
    ld_lds16(bP + (size_t)64 * ldb, bD + 4096);
    ld_lds16(bP + (size_t)96 * ldb, bD + 6144);

    for (int it = 0; it < nIter; ++it) {
        if (it + 1 < nIter) {
            int kt = (it + 1) << 6;
            int bsel = (it + 1) & 1;
            u16* ad = aD + bsel * 4096;
            u16* bd = bD + bsel * 8192;
            const u16* ap = aP + kt;
            const u16* bp = bP + kt;
            ld_lds16(ap, ad);
            ld_lds16(ap + (size_t)32 * lda, ad + 2048);
            ld_lds16(bp, bd);
            ld_lds16(bp + (size_t)32 * ldb, bd + 2048);
            ld_lds16(bp + (size_t)64 * ldb, bd + 4096);
            ld_lds16(bp + (size_t)96 * ldb, bd + 6144);
            asm volatile("s_waitcnt vmcnt(6)" ::: "memory");   // tile `it` loads done
        } else {
            asm volatile("s_waitcnt vmcnt(0)" ::: "memory");
        }
        asm volatile("s_barrier" ::: "memory");
        const u16* as = As + (it & 1) * 4096;
        const u16* bs = Bs + (it & 1) * 8192;
#pragma unroll
        for (int ks = 0; ks < 2; ks++) {
            bf16x8 af[2], bfr[4];
            int gsw = (ks * 4 + q) ^ (m16 & 7);
#pragma unroll
            for (int i = 0; i < 2; i++) {
                int m = wm * 32 + i * 16 + m16;
                af[i] = *(const bf16x8*)&as[m * 64 + gsw * 8];
            }
#pragma unroll
            for (int j = 0; j < 4; j++) {
                int n = wn * 64 + j * 16 + m16;
                bfr[j] = *(const bf16x8*)&bs[n * 64 + gsw * 8];
            }
#pragma unroll
            for (int i = 0; i < 2; i++)
#pragma unroll
                for (int j = 0; j < 4; j++)
                    acc[i][j] = __builtin_amdgcn_mfma_f32_16x16x32_bf16(af[i], bfr[j], acc[i][j], 0, 0, 0);
        }
        asm volatile("s_barrier" ::: "memory");
    }
}

// ---------------------------------------------------------------------------
// gates GEMM + fused LSTM cell. A=[256][2560]=[x|h] bf16, Bw gate-interleaved.
// Grid: 1-D 160, n-tile = lin%40 (same-n blocks share XCD L2 for B reuse).
// Epilogue: acc -> LDS [64][132] -> per-(b,j) cell update; h written bf16 to
// hA (next-step A slot) and optionally hB (next layer's x slot).
// ---------------------------------------------------------------------------
__global__ __launch_bounds__(256) void gemm_cell(
    const u16* __restrict__ A, const u16* __restrict__ Bw,
    const float* __restrict__ bih, const float* __restrict__ bhh,
    float* __restrict__ cst, u16* __restrict__ hA, u16* __restrict__ hB) {
    __shared__ __align__(16) u16 As[2 * 4096];
    __shared__ __align__(16) u16 Bs[2 * 8192];
    __shared__ __align__(16) float cb[64][132];

    int lin = blockIdx.x;
    int nb = lin % 40, mb = lin / 40;
    int n0 = nb * 128, m0 = mb * 64;

    f32x4 acc[2][4];
#pragma unroll
    for (int i = 0; i < 2; i++)
#pragma unroll
        for (int j = 0; j < 4; j++) acc[i][j] = (f32x4){0.f, 0.f, 0.f, 0.f};

    gemm_core(A, 2560, Bw, 2560, 2560, m0, n0, As, Bs, acc);

    int tid = threadIdx.x;
    int w = tid >> 6, l = tid & 63;
    int wm = w >> 1, wn = w & 1, q = l >> 4, m16 = l & 15;
#pragma unroll
    for (int i = 0; i < 2; i++)
#pragma unroll
        for (int j = 0; j < 4; j++)
#pragma unroll
            for (int r = 0; r < 4; r++)
                cb[wm * 32 + i * 16 + q * 4 + r][wn * 64 + j * 16 + m16] = acc[i][j][r];
    __syncthreads();

    int jt = tid & 31, bt0 = tid >> 5;
    int jg = (n0 >> 2) + jt;            // global hidden index 0..1279
    float bI = bih[jg] + bhh[jg];
    float bF = bih[1280 + jg] + bhh[1280 + jg];
    float bG = bih[2560 + jg] + bhh[2560 + jg];
    float bO = bih[3840 + jg] + bhh[3840 + jg];
#pragma unroll
    for (int p = 0; p < 8; p++) {
        int bt = bt0 + p * 8;
        float4 g4 = *(const float4*)&cb[bt][jt * 4];   // i,f,g,o
        int b = m0 + bt;
        float cv = cst[b * 1280 + jg];
        float cn = sigm(g4.y + bF) * cv + sigm(g4.x + bI) * tanh_f(g4.z + bG);
        cst[b * 1280 + jg] = cn;
        u16 hv = f2bf(sigm(g4.w + bO) * tanh_f(cn));
        hA[(size_t)b * 2560 + jg] = hv;
        if (hB) hB[(size_t)b * 2560 + jg] = hv;
    }
}

// ---------------------------------------------------------------------------
// Plain GEMM head: bias+relu. OUTBF16=0: fp32 C[ldc]. OUTBF16=1: bf16 with
// row remap s=b*5+a -> xh0[b*2560 + a*256 + col] (MLP layer-2 into x slot).
// ---------------------------------------------------------------------------
template <int OUTBF16>
__global__ __launch_bounds__(256) void gemm_head(
    const u16* __restrict__ A, int lda, const u16* __restrict__ Bw, int ldb,
    const float* __restrict__ bias, void* __restrict__ Cout, int ldc,
    int K, int nTiles) {
    __shared__ __align__(16) u16 As[2 * 4096];
    __shared__ __align__(16) u16 Bs[2 * 8192];

    int lin = blockIdx.x;
    int nb = lin % nTiles, mb = lin / nTiles;
    int n0 = nb * 128, m0 = mb * 64;

    f32x4 acc[2][4];
#pragma unroll
    for (int i = 0; i < 2; i++)
#pragma unroll
        for (int j = 0; j < 4; j++) acc[i][j] = (f32x4){0.f, 0.f, 0.f, 0.f};

    gemm_core(A, lda, Bw, ldb, K, m0, n0, As, Bs, acc);

    int tid = threadIdx.x;
    int w = tid >> 6, l = tid & 63;
    int wm = w >> 1, wn = w & 1, q = l >> 4, m16 = l & 15;
#pragma unroll
    for (int i = 0; i < 2; i++) {
        int row = m0 + wm * 32 + i * 16 + q * 4;
#pragma unroll
        for (int j = 0; j < 4; j++) {
            int col = n0 + wn * 64 + j * 16 + m16;
#pragma unroll
            for (int r = 0; r < 4; r++) {
                float v = fmaxf(acc[i][j][r] + bias[col], 0.f);
                int rw = row + r;
                if (OUTBF16) {
                    ((u16*)Cout)[(size_t)(rw / 5) * 2560 + (rw % 5) * 256 + col] = f2bf(v);
                } else {
                    ((float*)Cout)[(size_t)rw * ldc + col] = v;
                }
            }
        }
    }
}

// ---------------------------------------------------------------------------
// Fused: out head (y@w22^T + b22 + ins) -> d_out, teacher-select ins(t+1),
// MLP layer-1 -> act1 bf16 [1280][256]. One block per sample b (256 blocks).
// ---------------------------------------------------------------------------
template <int FIRST>
__global__ __launch_bounds__(256) void outmlp(
    const float* __restrict__ y, const float* __restrict__ w22,
    const float* __restrict__ b22, const float* __restrict__ inputs,
    const int* __restrict__ ps, const float* __restrict__ w11,
    const float* __restrict__ b11, float* __restrict__ out,
    float* __restrict__ ins_buf, u16* __restrict__ act1bf, int t) {
    __shared__ float red[4][20];
    __shared__ float ins_s[20];
    int b = blockIdx.x, tid = threadIdx.x;
    int w = tid >> 6, l = tid & 63;

    if (!FIRST) {
        float acc[20];
#pragma unroll
        for (int j = 0; j < 20; j++) acc[j] = 0.f;
        const float* yb = y + (size_t)b * 1280 + w * 320;
#pragma unroll
        for (int s = 0; s < 5; s++) {
            int k = w * 320 + s * 64 + l;
            float yv = yb[s * 64 + l];
#pragma unroll
            for (int j = 0; j < 20; j++) acc[j] = fmaf(yv, w22[j * 1280 + k], acc[j]);
        }
#pragma unroll
        for (int j = 0; j < 20; j++)
#pragma unroll
            for (int off = 32; off; off >>= 1) acc[j] += __shfl_xor(acc[j], off);
        if (l < 20) red[w][l] = acc[l];
        __syncthreads();
        if (tid < 20) {
            float o = red[0][tid] + red[1][tid] + red[2][tid] + red[3][tid]
                      + b22[tid] + ins_buf[b * 20 + tid];
            int a = tid >> 2, n = tid & 3;
            out[(((size_t)b * 5 + a) * 63 + t) * 4 + n] = o;
            float nx = (((t + 1) % ps[0]) == 0)
                           ? inputs[(((size_t)b * 5 + a) * 64 + (t + 1)) * 4 + n] : o;
            ins_s[tid] = nx;
            ins_buf[b * 20 + tid] = nx;
        }
    } else {
        if (tid < 20) {
            int a = tid >> 2, n = tid & 3;
            float nx = inputs[(((size_t)b * 5 + a) * 64) * 4 + n];
            ins_s[tid] = nx;
            ins_buf[b * 20 + tid] = nx;
        }
    }
    __syncthreads();

    // MLP layer-1: 5 agents x 256 units
    int j = tid;
    float4 wv = *(const float4*)(w11 + j * 4);
    float bb = b11[j];
#pragma unroll
    for (int g = 0; g < 5; g++) {
        float v = fmaf(wv.x, ins_s[g * 4],
                  fmaf(wv.y, ins_s[g * 4 + 1],
                  fmaf(wv.z, ins_s[g * 4 + 2],
                  fmaf(wv.w, ins_s[g * 4 + 3], bb))));
        act1bf[((size_t)b * 5 + g) * 256 + j] = f2bf(fmaxf(v, 0.f));
    }
}

// ---------------------------------------------------------------------------
extern "C" void kernel_launch(void* const* d_in, const int* in_sizes, int n_in,
                              void* d_out, int out_size, void* d_ws, size_t ws_size,
                              hipStream_t stream) {
    const float* inputs = (const float*)d_in[0];
    const float* w1_1 = (const float*)d_in[1];
    const float* b1_1 = (const float*)d_in[2];
    const float* w1_2 = (const float*)d_in[3];
    const float* b1_2 = (const float*)d_in[4];
    const float* w_ih = (const float*)d_in[5];
    const float* w_hh = (const float*)d_in[6];
    const float* b_ih = (const float*)d_in[7];
    const float* b_hh = (const float*)d_in[8];
    const float* w2_1 = (const float*)d_in[9];
    const float* b2_1 = (const float*)d_in[10];
    const float* w2_2 = (const float*)d_in[11];
    const float* b2_2 = (const float*)d_in[12];
    const int* ps = (const int*)d_in[13];
    float* out = (float*)d_out;

    char* ws = (char*)d_ws;
    size_t off = 0;
    auto alloc = [&](size_t bytes) -> void* {
        void* p = ws + off;
        off = (off + bytes + 255) & ~(size_t)255;
        return p;
    };
    u16* wcat   = (u16*)alloc(26214400ull * 2);  // [2][5120][2560] interleaved
    u16* w21_bf = (u16*)alloc(1638400ull * 2);   // [1280][1280]
    u16* w12_bf = (u16*)alloc(65536ull * 2);     // [256][256]
    u16* xh0a   = (u16*)alloc(655360ull * 2);    // [256][2560] = [x | h0]
    u16* xh0b   = (u16*)alloc(655360ull * 2);
    u16* xh1a   = (u16*)alloc(655360ull * 2);    // [256][2560] = [h0 | h1]
    u16* xh1b   = (u16*)alloc(655360ull * 2);
    float* c_st = (float*)alloc(655360ull * 4);  // [2][256][1280]
    float* yb   = (float*)alloc(327680ull * 4);  // [256][1280]
    u16* act1bf = (u16*)alloc(327680ull * 2);    // [1280][256]
    float* ins_b = (float*)alloc(5120ull * 4);   // [256][20]

    u16* xh0[2] = {xh0a, xh0b};
    u16* xh1[2] = {xh1a, xh1b};
    float* c0 = c_st;
    float* c1 = c_st + 327680;

    // per-launch weight prep + state init
    cvt_wcat<<<25600, 256, 0, stream>>>(w_ih, w_hh, wcat);
    cvt_kernel<<<1600, 256, 0, stream>>>(w2_1, w21_bf, 1638400);
    cvt_kernel<<<64, 256, 0, stream>>>(w1_2, w12_bf, 65536);
    hipMemsetAsync(xh0a, 0, 655360ull * 2, stream);
    hipMemsetAsync(xh0b, 0, 655360ull * 2, stream);
    hipMemsetAsync(xh1a, 0, 655360ull * 2, stream);
    hipMemsetAsync(xh1b, 0, 655360ull * 2, stream);
    hipMemsetAsync(c_st, 0, 655360ull * 4, stream);

    // t = -1: select ins(0), MLP layer-1, then layer-2 GEMM -> x(0)
    outmlp<1><<<256, 256, 0, stream>>>(yb, w2_2, b2_2, inputs, ps, w1_1, b1_1,
                                       out, ins_b, act1bf, -1);
    gemm_head<1><<<40, 256, 0, stream>>>(act1bf, 256, w12_bf, 256, b1_2,
                                         xh0[0], 0, 256, 2);

    for (int t = 0; t < 63; t++) {
        int p = t & 1;
        // layer 0: gates = [x|h0] @ wcat0^T, fused cell -> h0, c0
        gemm_cell<<<160, 256, 0, stream>>>(xh0[p], wcat, b_ih, b_hh, c0,
                                           xh0[1 - p] + 1280, xh1[p]);
        // layer 1: gates = [h0|h1] @ wcat1^T, fused cell -> h1, c1
        gemm_cell<<<160, 256, 0, stream>>>(xh1[p], wcat + 13107200, b_ih + 5120,
                                           b_hh + 5120, c1, xh1[1 - p] + 1280,
                                           (u16*)nullptr);
        // y = relu(h1 @ w21^T + b21)
        gemm_head<0><<<40, 256, 0, stream>>>(xh1[1 - p] + 1280, 2560, w21_bf, 1280,
                                             b2_1, yb, 1280, 1280, 10);
        // out head + residual + ins(t+1) select + MLP layer-1
        outmlp<0><<<256, 256, 0, stream>>>(yb, w2_2, b2_2, inputs, ps, w1_1, b1_1,
                                           out, ins_b, act1bf, t);
        // MLP layer-2 -> x(t+1)
        gemm_head<1><<<40, 256, 0, stream>>>(act1bf, 256, w12_bf, 256, b1_2,
                                             xh0[(t + 1) & 1], 0, 256, 2);
    }
}